// Round 21
// baseline (576.628 us; speedup 1.0000x reference)
//
#include <hip/hip_runtime.h>
#include <hip/hip_bf16.h>

// Graph-transformer MHA layer. N=50000, E=1600000, IN_DIM=64, H=8, D=8.
// Outputs: h_out [N*64] then e_out [E*64], fp32, concatenated in d_out.
//
// R21 (from R20):
//  - edge kernel: e-stream staged through LDS. 8 fully-coalesced 1KB loads
//    per 32-edge half (8x128B transactions each) replace 8 scattered-row
//    loads (~64x16B transactions each): ~8x fewer TA transactions on the
//    410MB e stream. Fragment k-permutation k = 32hi+8ks+4g+i applied to
//    BOTH A (We) and B (e) operands (GEMM-invariant) so each lane's LDS
//    fragment reads are clean swizzled float4s. The 8KB e-stage buffer is
//    reused as the two 4KB out-staging buffers (DS ops in-order per wave
//    -> WAR safe); LDS stays 32KB/block.
//  - rest = R20 (bf16 Q/K/V + gates, fused proj+rank, scan, reorder,
//    1-wave-per-node aggregate).

using short8 = __attribute__((ext_vector_type(8))) short;
using f32x16 = __attribute__((ext_vector_type(16))) float;

__device__ __forceinline__ short f2bf(float f) {
    __hip_bfloat16 b = __float2bfloat16(f);     // RNE; pairs fuse to v_cvt_pk_bf16_f32
    return __builtin_bit_cast(short, b);
}
__device__ __forceinline__ unsigned short f2bfu(float f) {
    __hip_bfloat16 b = __float2bfloat16(f);
    return __builtin_bit_cast(unsigned short, b);
}
__device__ __forceinline__ float bf2f(unsigned short s) {
    unsigned u = ((unsigned)s) << 16;
    return __builtin_bit_cast(float, u);
}

// ---------------- fused node projection (y=0..2, bf16 out) + rank (y=3) ----------------
__global__ __launch_bounds__(256)
void proj_rank_kernel(const float* __restrict__ hsrc,
                      const float* __restrict__ Wq, const float* __restrict__ bq,
                      const float* __restrict__ Wk, const float* __restrict__ bk,
                      const float* __restrict__ Wv, const float* __restrict__ bv,
                      unsigned short* __restrict__ Q, unsigned short* __restrict__ K,
                      unsigned short* __restrict__ V,
                      const int* __restrict__ dst, int* __restrict__ counts,
                      int* __restrict__ rank, int n, int E)
{
    if (blockIdx.y == 3) {
        int i = blockIdx.x * 256 + threadIdx.x;
        const int stride = gridDim.x * 256;
        for (; i < E; i += stride) {
            rank[i] = atomicAdd(&counts[dst[i]], 1);
        }
        return;
    }

    const float* W;
    const float* b;
    unsigned short* out;
    if (blockIdx.y == 0)      { W = Wq; b = bq; out = Q; }
    else if (blockIdx.y == 1) { W = Wk; b = bk; out = K; }
    else                      { W = Wv; b = bv; out = V; }

    const int t    = threadIdx.x;
    const int lane = t & 63;
    const int w    = t >> 6;

    float wcol[64];
#pragma unroll
    for (int k = 0; k < 64; ++k) wcol[k] = W[k * 64 + lane];
    const float bias = b[lane];

    __shared__ float4 sh[16][16];
    const float4* __restrict__ h4 = (const float4*)hsrc;

    const int ngroups = (n + 15) >> 4;
    for (int g = blockIdx.x; g < ngroups; g += gridDim.x) {
        const int base = g << 4;
        {
            const int rs = t >> 4, c4 = t & 15;
            float4 v = make_float4(0.f, 0.f, 0.f, 0.f);
            if (base + rs < n) v = h4[(size_t)(base + rs) * 16 + c4];
            __syncthreads();
            sh[rs][c4] = v;
            __syncthreads();
        }
        float acc0 = bias, acc1 = bias, acc2 = bias, acc3 = bias;
#pragma unroll
        for (int k4 = 0; k4 < 16; ++k4) {
            const float w0 = wcol[k4 * 4 + 0], w1 = wcol[k4 * 4 + 1];
            const float w2 = wcol[k4 * 4 + 2], w3 = wcol[k4 * 4 + 3];
            const float4 a = sh[w * 4 + 0][k4];
            const float4 bb = sh[w * 4 + 1][k4];
            const float4 c = sh[w * 4 + 2][k4];
            const float4 d = sh[w * 4 + 3][k4];
            acc0 = fmaf(a.w,  w3, fmaf(a.z,  w2, fmaf(a.y,  w1, fmaf(a.x,  w0, acc0))));
            acc1 = fmaf(bb.w, w3, fmaf(bb.z, w2, fmaf(bb.y, w1, fmaf(bb.x, w0, acc1))));
            acc2 = fmaf(c.w,  w3, fmaf(c.z,  w2, fmaf(c.y,  w1, fmaf(c.x,  w0, acc2))));
            acc3 = fmaf(d.w,  w3, fmaf(d.z,  w2, fmaf(d.y,  w1, fmaf(d.x,  w0, acc3))));
        }
        const int n0 = base + w * 4;
        if (n0 + 0 < n) out[(size_t)(n0 + 0) * 64 + lane] = f2bfu(acc0);
        if (n0 + 1 < n) out[(size_t)(n0 + 1) * 64 + lane] = f2bfu(acc1);
        if (n0 + 2 < n) out[(size_t)(n0 + 2) * 64 + lane] = f2bfu(acc2);
        if (n0 + 3 < n) out[(size_t)(n0 + 3) * 64 + lane] = f2bfu(acc3);
    }
}

// ---------------- multi-block exclusive scan (3 kernels) ----------------
__global__ __launch_bounds__(1024)
void scan1_kernel(const int* __restrict__ counts, int* __restrict__ offsets,
                  int* __restrict__ bsum, int n)
{
    const int t = threadIdx.x;
    const int lane = t & 63;
    const int w = t >> 6;
    __shared__ int wsum[16];
    const int i = blockIdx.x * 1024 + t;
    const int v = (i < n) ? counts[i] : 0;
    int x = v;
#pragma unroll
    for (int d = 1; d < 64; d <<= 1) {
        int y = __shfl_up(x, d);
        if (lane >= d) x += y;
    }
    if (lane == 63) wsum[w] = x;
    __syncthreads();
    if (w == 0 && lane < 16) {
        int s = wsum[lane];
#pragma unroll
        for (int d = 1; d < 16; d <<= 1) {
            int y = __shfl_up(s, d);
            if (lane >= d) s += y;
        }
        wsum[lane] = s;
    }
    __syncthreads();
    const int excl = ((w == 0) ? 0 : wsum[w - 1]) + (x - v);
    if (i < n) offsets[i] = excl;
    if (t == 1023) bsum[blockIdx.x] = excl + v;
}

__global__ __launch_bounds__(64)
void scan2_kernel(int* __restrict__ bsum, int nb)
{
    const int lane = threadIdx.x;
    const int v = (lane < nb) ? bsum[lane] : 0;
    int x = v;
#pragma unroll
    for (int d = 1; d < 64; d <<= 1) {
        int y = __shfl_up(x, d);
        if (lane >= d) x += y;
    }
    if (lane < nb) bsum[lane] = x - v;   // exclusive
}

__global__ __launch_bounds__(1024)
void scan3_kernel(int* __restrict__ offsets, const int* __restrict__ bsum,
                  int n, int E)
{
    const int i = blockIdx.x * 1024 + threadIdx.x;
    if (i < n) offsets[i] += bsum[blockIdx.x];
    if (blockIdx.x == 0 && threadIdx.x == 0) offsets[n] = E;
}

// ---------------- edge kernel v21: MFMA, coalesced e staging via LDS ----------------
__global__ __launch_bounds__(256)
void edge_kernel(const float* __restrict__ e,
                 const float* __restrict__ We, const float* __restrict__ be,
                 const int* __restrict__ src, const int* __restrict__ dst,
                 const unsigned short* __restrict__ Q,
                 const unsigned short* __restrict__ K,
                 float* __restrict__ e_out, unsigned short* __restrict__ sg, int E)
{
    // 8 KB per wave: e-stage (512 f4) reused as two 4KB out buffers after
    // the fragment reads retire (DS ops are in-order per wave -> WAR safe).
    __shared__ float4 stg[4][512];
    const int t    = threadIdx.x;
    const int lane = t & 63;
    const int wu   = __builtin_amdgcn_readfirstlane(t >> 6);
    const int lid  = lane & 31;
    const int hi   = lane >> 5;
    float4* const myS = stg[wu];
    const float inv = 0.35355339059327373f;         // 1/sqrt(8)

    // A fragments (We^T) with joint k-permutation k_phys = 32hi + 8ks + 4g + i.
    // A[jh][ks] elem (4g+i) holds We[32hi + 8ks + 4g + i][32jh + lid].
    short8 Afr[2][4];
#pragma unroll
    for (int jh = 0; jh < 2; ++jh)
#pragma unroll
        for (int ks = 0; ks < 4; ++ks)
#pragma unroll
            for (int g = 0; g < 2; ++g)
#pragma unroll
                for (int i = 0; i < 4; ++i)
                    Afr[jh][ks][4 * g + i] =
                        f2bf(We[(32 * hi + 8 * ks + 4 * g + i) * 64 + 32 * jh + lid]);

    const int ntiles = (E + 63) >> 6;
    for (int tb = blockIdx.x * 4 + wu; tb < ntiles; tb += gridDim.x * 4) {
        const int base = tb << 6;

#pragma unroll
        for (int eh = 0; eh < 2; ++eh) {
            const int half = base + eh * 32;                // first edge of half
            const int erow_i = half + lid;
            const int erc = erow_i < E ? erow_i : (E - 1);
            const int se = src[erc];
            const int de = dst[erc];

            // K/Q bf16 gathers issued early (independent of e staging)
            const unsigned short* kb = K + (size_t)se * 64 + 4 * hi;
            const unsigned short* qb = Q + (size_t)de * 64 + 4 * hi;
            ushort4 kvr[2][4], qvr[2][4];
#pragma unroll
            for (int jh = 0; jh < 2; ++jh)
#pragma unroll
                for (int hd = 0; hd < 4; ++hd) {
                    kvr[jh][hd] = *(const ushort4*)(kb + 32 * jh + 8 * hd);
                    qvr[jh][hd] = *(const ushort4*)(qb + 32 * jh + 8 * hd);
                }

            // ---- coalesced e stage: 8 x 1KB contiguous loads -> swizzled LDS ----
            {
                const float4* esrc = (const float4*)e + (size_t)half * 16;
                const long lim = ((long)E - half) * 16;     // valid f4 count
#pragma unroll
                for (int q = 0; q < 8; ++q) {
                    const int f = q * 64 + lane;            // f4 index in half-tile
                    float4 v = make_float4(0.f, 0.f, 0.f, 0.f);
                    if ((long)f < lim) v = esrc[f];
                    const int r = f >> 4, c = f & 15;       // edge row, f4 col
                    myS[r * 16 + (c ^ (r & 15))] = v;
                }
            }
            asm volatile("s_waitcnt lgkmcnt(0)" ::: "memory");

            // ---- per-lane fragment reads: lane (lid,hi) holds k in [32hi,32hi+32) ----
            float4 ef[8];                                    // ef[2ks+g], k = 32hi+8ks+4g+i
#pragma unroll
            for (int ks = 0; ks < 4; ++ks)
#pragma unroll
                for (int g = 0; g < 2; ++g) {
                    const int c = 8 * hi + 2 * ks + g;
                    ef[2 * ks + g] = myS[lid * 16 + (c ^ (lid & 15))];
                }

            short8 Bfr[4];
#pragma unroll
            for (int ks = 0; ks < 4; ++ks) {
                const float4 pa = ef[2 * ks], pb = ef[2 * ks + 1];
                Bfr[ks][0] = f2bf(pa.x); Bfr[ks][1] = f2bf(pa.y);
                Bfr[ks][2] = f2bf(pa.z); Bfr[ks][3] = f2bf(pa.w);
                Bfr[ks][4] = f2bf(pb.x); Bfr[ks][5] = f2bf(pb.y);
                Bfr[ks][6] = f2bf(pb.z); Bfr[ks][7] = f2bf(pb.w);
            }

            float gate[8];
#pragma unroll
            for (int jh = 0; jh < 2; ++jh) {
                // out buffer: reuse e-stage halves (jh0 -> f4[0..255], jh1 -> f4[256..511])
                float4* const buf = myS + jh * 256;

                f32x16 D = {};
#pragma unroll
                for (int ks = 0; ks < 4; ++ks)
                    D = __builtin_amdgcn_mfma_f32_32x32x16_bf16(
                            Afr[jh][ks], Bfr[ks], D, 0, 0, 0);

                // epilogue: preloaded bf16 kv/qv; stage + head sums
#pragma unroll
                for (int hd = 0; hd < 4; ++hd) {
                    const float4 bev = *(const float4*)(be + 32 * jh + 8 * hd + 4 * hi);
                    const ushort4 kr = kvr[jh][hd];
                    const ushort4 qr = qvr[jh][hd];
                    const float s0 = bf2f(kr.x) * bf2f(qr.x) * inv * (D[4 * hd + 0] + bev.x);
                    const float s1 = bf2f(kr.y) * bf2f(qr.y) * inv * (D[4 * hd + 1] + bev.y);
                    const float s2 = bf2f(kr.z) * bf2f(qr.z) * inv * (D[4 * hd + 2] + bev.z);
                    const float s3 = bf2f(kr.w) * bf2f(qr.w) * inv * (D[4 * hd + 3] + bev.w);
                    const int c4 = (2 * hd + hi) ^ (lid & 7);       // XOR swizzle
                    buf[lid * 8 + c4] = make_float4(s0, s1, s2, s3);
                    float pp = (s0 + s1) + (s2 + s3);
                    const float full = pp + __shfl_xor(pp, 32);     // head = 4jh+hd
                    gate[jh * 4 + hd] = expf(fminf(fmaxf(full, -5.f), 5.f));
                }

                // readout: 4 x 64-lane dwordx4 stores of 128B half-rows
                const int r8 = lane >> 3, m = lane & 7;
#pragma unroll
                for (int it = 0; it < 4; ++it) {
                    const int row = it * 8 + r8;                    // edge row 0..31
                    const int edge2 = half + row;
                    const float4 v = buf[row * 8 + (m ^ (row & 7))];
                    if (edge2 < E)
                        *((float4*)e_out + (size_t)edge2 * 16 + jh * 8 + m) = v;
                }
            }

            // coalesced bf16 gate write: 32 edges x 16B contiguous
            if (erow_i < E) {
                const ushort4 g = (hi == 0)
                    ? make_ushort4(f2bfu(gate[0]), f2bfu(gate[1]), f2bfu(gate[2]), f2bfu(gate[3]))
                    : make_ushort4(f2bfu(gate[4]), f2bfu(gate[5]), f2bfu(gate[6]), f2bfu(gate[7]));
                *(ushort4*)(sg + (size_t)erow_i * 8 + hi * 4) = g;
            }
        }
    }
}

// ---------------- reorder kernel: coalesced read -> sorted scatter (bf16) ----------------
__global__ __launch_bounds__(256)
void reorder_kernel(const unsigned short* __restrict__ sg, const int* __restrict__ src,
                    const int* __restrict__ dst, const int* __restrict__ rank,
                    const int* __restrict__ offs,
                    unsigned short* __restrict__ s_sorted, int* __restrict__ src_sorted,
                    int E)
{
    int i = blockIdx.x * 256 + threadIdx.x;
    const int stride = gridDim.x * 256;
    for (; i < E; i += stride) {
        const int rk = offs[dst[i]] + rank[i];
        const uint4 g = *(const uint4*)(sg + (size_t)i * 8);     // 16B = 8 bf16
        *(uint4*)(s_sorted + (size_t)rk * 8) = g;
        src_sorted[rk] = src[i];
    }
}

// ---------------- aggregation: one wave per node, bf16 V + bf16 gates ----------------
__global__ __launch_bounds__(64, 8)
void aggregate_kernel(const int* __restrict__ offsets,
                      const int* __restrict__ src_sorted,
                      const unsigned short* __restrict__ s_sorted,
                      const unsigned short* __restrict__ V,
                      float* __restrict__ hout, int n)
{
    const int w = blockIdx.x;           // one wave = one block = one node
    const int lane = threadIdx.x;
    if (w >= n) return;
    const int o0 = offsets[w], o1 = offsets[w + 1];
    const int head = lane >> 3;
    float acc = 0.f, zacc = 0.f;
    int j = o0;
    for (; j + 8 <= o1; j += 8) {
        int   sv[8];
        float ss[8];
#pragma unroll
        for (int q = 0; q < 8; ++q) {
            sv[q] = src_sorted[j + q];
            ss[q] = bf2f(s_sorted[(size_t)(j + q) * 8 + head]);
        }
        float vv[8];
#pragma unroll
        for (int q = 0; q < 8; ++q)
            vv[q] = bf2f(V[(size_t)sv[q] * 64 + lane]);
#pragma unroll
        for (int q = 0; q < 8; ++q) {
            acc = fmaf(vv[q], ss[q], acc);
            zacc += ss[q];
        }
    }
    for (; j < o1; ++j) {
        const int sv = src_sorted[j];
        const float s = bf2f(s_sorted[(size_t)j * 8 + head]);
        acc = fmaf(bf2f(V[(size_t)sv * 64 + lane]), s, acc);
        zacc += s;
    }
    hout[(size_t)w * 64 + lane] = acc / (zacc + 1e-6f);
}

extern "C" void kernel_launch(void* const* d_in, const int* in_sizes, int n_in,
                              void* d_out, int out_size, void* d_ws, size_t ws_size,
                              hipStream_t stream)
{
    const float* h  = (const float*)d_in[0];
    const float* e  = (const float*)d_in[1];
    const float* Wq = (const float*)d_in[2];
    const float* bq = (const float*)d_in[3];
    const float* Wk = (const float*)d_in[4];
    const float* bk = (const float*)d_in[5];
    const float* Wv = (const float*)d_in[6];
    const float* bv = (const float*)d_in[7];
    const float* We = (const float*)d_in[8];
    const float* be = (const float*)d_in[9];
    const int* src  = (const int*)d_in[10];
    const int* dst  = (const int*)d_in[11];

    const int N = in_sizes[0] / 64;
    const int E = in_sizes[1] / 64;

    float* hout  = (float*)d_out;                    // [N*64]
    float* e_out = (float*)d_out + (size_t)N * 64;   // [E*64]

    // workspace layout
    char* ws = (char*)d_ws;
    unsigned short* Q = (unsigned short*)ws; ws += (size_t)N * 64 * sizeof(unsigned short);
    unsigned short* K = (unsigned short*)ws; ws += (size_t)N * 64 * sizeof(unsigned short);
    unsigned short* V = (unsigned short*)ws; ws += (size_t)N * 64 * sizeof(unsigned short);
    unsigned short* sg = (unsigned short*)ws;       ws += (size_t)E * 8 * sizeof(unsigned short);
    unsigned short* s_sorted = (unsigned short*)ws; ws += (size_t)E * 8 * sizeof(unsigned short);
    int* src_sorted = (int*)ws;            ws += (size_t)E * sizeof(int);
    int* rank = (int*)ws;                  ws += (size_t)E * sizeof(int);
    int* counts  = (int*)ws;               ws += (size_t)N * sizeof(int);
    int* offsets = (int*)ws;               ws += (size_t)(N + 1) * sizeof(int);
    int* bsum    = (int*)ws;               ws += 64 * sizeof(int);

    hipMemsetAsync(counts, 0, (size_t)N * sizeof(int), stream);

    // 1) fused Q,K,V projections (bf16 out) + rank (independent, overlapped)
    proj_rank_kernel<<<dim3(512, 4), dim3(256), 0, stream>>>(
        h, Wq, bq, Wk, bk, Wv, bv, Q, K, V, dst, counts, rank, N, E);

    // 2) exclusive scan -> offsets (multi-block, 3 kernels)
    const int nb = (N + 1023) / 1024;
    scan1_kernel<<<dim3(nb), dim3(1024), 0, stream>>>(counts, offsets, bsum, N);
    scan2_kernel<<<dim3(1), dim3(64), 0, stream>>>(bsum, nb);
    scan3_kernel<<<dim3(nb), dim3(1024), 0, stream>>>(offsets, bsum, N, E);

    // 3) edge pass: MFMA, coalesced e staging via LDS, bf16 K/Q + gates
    edge_kernel<<<dim3(1280), dim3(256), 0, stream>>>(
        e, We, be, src, dst, Q, K, e_out, sg, E);

    // 4) reorder: coalesced bf16 reads -> sorted scatter (TLP-rich)
    reorder_kernel<<<dim3(2048), dim3(256), 0, stream>>>(
        sg, src, dst, rank, offsets, s_sorted, src_sorted, E);

    // 5) aggregate: one 64-thread block per node, bf16 V + gates
    aggregate_kernel<<<dim3(N), dim3(64), 0, stream>>>(
        offsets, src_sorted, s_sorted, V, hout, N);
}

// Round 22
// 481.209 us; speedup vs baseline: 1.1983x; 1.1983x over previous
//
#include <hip/hip_runtime.h>
#include <hip/hip_bf16.h>

// Graph-transformer MHA layer. N=50000, E=1600000, IN_DIM=64, H=8, D=8.
// Outputs: h_out [N*64] then e_out [E*64], fp32, concatenated in d_out.
//
// R22 = revert to R20 (best measured: 482 us).
// R21's coalesced-LDS e-staging regressed (+94us): the stage->lgkmcnt(0)->
// read chain serialized each half-tile; per-lane 16B-contiguous e-row loads
// were never transaction-limited. Mechanism classes now exhausted for edge:
// scheduling (R13/17/18), occupancy (R9/11), bytes (R19 win, now floor'd),
// transactions (R21). Edge ~249us vs 136us pure-stream floor; K/Q gather
// latency is the irreducible residual for this structure.

using short8 = __attribute__((ext_vector_type(8))) short;
using f32x16 = __attribute__((ext_vector_type(16))) float;

__device__ __forceinline__ short f2bf(float f) {
    __hip_bfloat16 b = __float2bfloat16(f);     // RNE; pairs fuse to v_cvt_pk_bf16_f32
    return __builtin_bit_cast(short, b);
}
__device__ __forceinline__ unsigned short f2bfu(float f) {
    __hip_bfloat16 b = __float2bfloat16(f);
    return __builtin_bit_cast(unsigned short, b);
}
__device__ __forceinline__ float bf2f(unsigned short s) {
    unsigned u = ((unsigned)s) << 16;
    return __builtin_bit_cast(float, u);
}

// ---------------- fused node projection (y=0..2, bf16 out) + rank (y=3) ----------------
__global__ __launch_bounds__(256)
void proj_rank_kernel(const float* __restrict__ hsrc,
                      const float* __restrict__ Wq, const float* __restrict__ bq,
                      const float* __restrict__ Wk, const float* __restrict__ bk,
                      const float* __restrict__ Wv, const float* __restrict__ bv,
                      unsigned short* __restrict__ Q, unsigned short* __restrict__ K,
                      unsigned short* __restrict__ V,
                      const int* __restrict__ dst, int* __restrict__ counts,
                      int* __restrict__ rank, int n, int E)
{
    if (blockIdx.y == 3) {
        int i = blockIdx.x * 256 + threadIdx.x;
        const int stride = gridDim.x * 256;
        for (; i < E; i += stride) {
            rank[i] = atomicAdd(&counts[dst[i]], 1);
        }
        return;
    }

    const float* W;
    const float* b;
    unsigned short* out;
    if (blockIdx.y == 0)      { W = Wq; b = bq; out = Q; }
    else if (blockIdx.y == 1) { W = Wk; b = bk; out = K; }
    else                      { W = Wv; b = bv; out = V; }

    const int t    = threadIdx.x;
    const int lane = t & 63;
    const int w    = t >> 6;

    float wcol[64];
#pragma unroll
    for (int k = 0; k < 64; ++k) wcol[k] = W[k * 64 + lane];
    const float bias = b[lane];

    __shared__ float4 sh[16][16];
    const float4* __restrict__ h4 = (const float4*)hsrc;

    const int ngroups = (n + 15) >> 4;
    for (int g = blockIdx.x; g < ngroups; g += gridDim.x) {
        const int base = g << 4;
        {
            const int rs = t >> 4, c4 = t & 15;
            float4 v = make_float4(0.f, 0.f, 0.f, 0.f);
            if (base + rs < n) v = h4[(size_t)(base + rs) * 16 + c4];
            __syncthreads();
            sh[rs][c4] = v;
            __syncthreads();
        }
        float acc0 = bias, acc1 = bias, acc2 = bias, acc3 = bias;
#pragma unroll
        for (int k4 = 0; k4 < 16; ++k4) {
            const float w0 = wcol[k4 * 4 + 0], w1 = wcol[k4 * 4 + 1];
            const float w2 = wcol[k4 * 4 + 2], w3 = wcol[k4 * 4 + 3];
            const float4 a = sh[w * 4 + 0][k4];
            const float4 bb = sh[w * 4 + 1][k4];
            const float4 c = sh[w * 4 + 2][k4];
            const float4 d = sh[w * 4 + 3][k4];
            acc0 = fmaf(a.w,  w3, fmaf(a.z,  w2, fmaf(a.y,  w1, fmaf(a.x,  w0, acc0))));
            acc1 = fmaf(bb.w, w3, fmaf(bb.z, w2, fmaf(bb.y, w1, fmaf(bb.x, w0, acc1))));
            acc2 = fmaf(c.w,  w3, fmaf(c.z,  w2, fmaf(c.y,  w1, fmaf(c.x,  w0, acc2))));
            acc3 = fmaf(d.w,  w3, fmaf(d.z,  w2, fmaf(d.y,  w1, fmaf(d.x,  w0, acc3))));
        }
        const int n0 = base + w * 4;
        if (n0 + 0 < n) out[(size_t)(n0 + 0) * 64 + lane] = f2bfu(acc0);
        if (n0 + 1 < n) out[(size_t)(n0 + 1) * 64 + lane] = f2bfu(acc1);
        if (n0 + 2 < n) out[(size_t)(n0 + 2) * 64 + lane] = f2bfu(acc2);
        if (n0 + 3 < n) out[(size_t)(n0 + 3) * 64 + lane] = f2bfu(acc3);
    }
}

// ---------------- multi-block exclusive scan (3 kernels) ----------------
__global__ __launch_bounds__(1024)
void scan1_kernel(const int* __restrict__ counts, int* __restrict__ offsets,
                  int* __restrict__ bsum, int n)
{
    const int t = threadIdx.x;
    const int lane = t & 63;
    const int w = t >> 6;
    __shared__ int wsum[16];
    const int i = blockIdx.x * 1024 + t;
    const int v = (i < n) ? counts[i] : 0;
    int x = v;
#pragma unroll
    for (int d = 1; d < 64; d <<= 1) {
        int y = __shfl_up(x, d);
        if (lane >= d) x += y;
    }
    if (lane == 63) wsum[w] = x;
    __syncthreads();
    if (w == 0 && lane < 16) {
        int s = wsum[lane];
#pragma unroll
        for (int d = 1; d < 16; d <<= 1) {
            int y = __shfl_up(s, d);
            if (lane >= d) s += y;
        }
        wsum[lane] = s;
    }
    __syncthreads();
    const int excl = ((w == 0) ? 0 : wsum[w - 1]) + (x - v);
    if (i < n) offsets[i] = excl;
    if (t == 1023) bsum[blockIdx.x] = excl + v;
}

__global__ __launch_bounds__(64)
void scan2_kernel(int* __restrict__ bsum, int nb)
{
    const int lane = threadIdx.x;
    const int v = (lane < nb) ? bsum[lane] : 0;
    int x = v;
#pragma unroll
    for (int d = 1; d < 64; d <<= 1) {
        int y = __shfl_up(x, d);
        if (lane >= d) x += y;
    }
    if (lane < nb) bsum[lane] = x - v;   // exclusive
}

__global__ __launch_bounds__(1024)
void scan3_kernel(int* __restrict__ offsets, const int* __restrict__ bsum,
                  int n, int E)
{
    const int i = blockIdx.x * 1024 + threadIdx.x;
    if (i < n) offsets[i] += bsum[blockIdx.x];
    if (blockIdx.x == 0 && threadIdx.x == 0) offsets[n] = E;
}

// ---------------- edge kernel (R20 form): MFMA, dbuf LDS, bf16 K/Q + gates ----------------
__global__ __launch_bounds__(256)
void edge_kernel(const float* __restrict__ e,
                 const float* __restrict__ We, const float* __restrict__ be,
                 const int* __restrict__ src, const int* __restrict__ dst,
                 const unsigned short* __restrict__ Q,
                 const unsigned short* __restrict__ K,
                 float* __restrict__ e_out, unsigned short* __restrict__ sg, int E)
{
    __shared__ float4 tile4[4][2][32 * 8];          // 2x4KB per wave, XOR-swizzled
    const int t    = threadIdx.x;
    const int lane = t & 63;
    const int wu   = __builtin_amdgcn_readfirstlane(t >> 6);
    const int lid  = lane & 31;
    const int hi   = lane >> 5;
    const float inv = 0.35355339059327373f;         // 1/sqrt(8)

    // A fragments (We^T), loaded once per wave.
    // A[jh][ks] elem (4g+i) holds We[k = 16ks + 8g + 4hi + i][j = 32jh + lid].
    short8 Afr[2][4];
#pragma unroll
    for (int jh = 0; jh < 2; ++jh)
#pragma unroll
        for (int ks = 0; ks < 4; ++ks)
#pragma unroll
            for (int g = 0; g < 2; ++g)
#pragma unroll
                for (int i = 0; i < 4; ++i)
                    Afr[jh][ks][4 * g + i] =
                        f2bf(We[(16 * ks + 8 * g + 4 * hi + i) * 64 + 32 * jh + lid]);

    const int ntiles = (E + 63) >> 6;
    for (int tb = blockIdx.x * 4 + wu; tb < ntiles; tb += gridDim.x * 4) {
        const int base = tb << 6;

#pragma unroll
        for (int eh = 0; eh < 2; ++eh) {
            const int erow_i = base + eh * 32 + lid;
            const int erc = erow_i < E ? erow_i : (E - 1);
            const int se = src[erc];
            const int de = dst[erc];

            // e row loads issued first
            const float* er = e + (size_t)erc * 64 + 4 * hi;
            float4 p0 = *(const float4*)(er + 0),  p1 = *(const float4*)(er + 8);
            float4 p2 = *(const float4*)(er + 16), p3 = *(const float4*)(er + 24);
            float4 p4 = *(const float4*)(er + 32), p5 = *(const float4*)(er + 40);
            float4 p6 = *(const float4*)(er + 48), p7 = *(const float4*)(er + 56);

            // K/Q bf16 rows for BOTH jh preloaded (16 x 8B gathers in flight)
            const unsigned short* kb = K + (size_t)se * 64 + 4 * hi;
            const unsigned short* qb = Q + (size_t)de * 64 + 4 * hi;
            ushort4 kvr[2][4], qvr[2][4];
#pragma unroll
            for (int jh = 0; jh < 2; ++jh)
#pragma unroll
                for (int hd = 0; hd < 4; ++hd) {
                    kvr[jh][hd] = *(const ushort4*)(kb + 32 * jh + 8 * hd);
                    qvr[jh][hd] = *(const ushort4*)(qb + 32 * jh + 8 * hd);
                }

            // cvt B fragments: elem (4g+i) = e[row][k = 16ks + 8g + 4hi + i]
            short8 Bfr[4];
#pragma unroll
            for (int ks = 0; ks < 4; ++ks) {
                const float4 pa = (ks == 0) ? p0 : (ks == 1) ? p2 : (ks == 2) ? p4 : p6;
                const float4 pb = (ks == 0) ? p1 : (ks == 1) ? p3 : (ks == 2) ? p5 : p7;
                Bfr[ks][0] = f2bf(pa.x); Bfr[ks][1] = f2bf(pa.y);
                Bfr[ks][2] = f2bf(pa.z); Bfr[ks][3] = f2bf(pa.w);
                Bfr[ks][4] = f2bf(pb.x); Bfr[ks][5] = f2bf(pb.y);
                Bfr[ks][6] = f2bf(pb.z); Bfr[ks][7] = f2bf(pb.w);
            }

            float gate[8];
#pragma unroll
            for (int jh = 0; jh < 2; ++jh) {
                // phase buffer alternates each (eh,jh) phase -> WAR distance 2
                float4* const buf = tile4[wu][jh];

                f32x16 D = {};
#pragma unroll
                for (int ks = 0; ks < 4; ++ks)
                    D = __builtin_amdgcn_mfma_f32_32x32x16_bf16(
                            Afr[jh][ks], Bfr[ks], D, 0, 0, 0);

                // epilogue: preloaded bf16 kv/qv; stage + head sums
#pragma unroll
                for (int hd = 0; hd < 4; ++hd) {
                    const float4 bev = *(const float4*)(be + 32 * jh + 8 * hd + 4 * hi);
                    const ushort4 kr = kvr[jh][hd];
                    const ushort4 qr = qvr[jh][hd];
                    const float s0 = bf2f(kr.x) * bf2f(qr.x) * inv * (D[4 * hd + 0] + bev.x);
                    const float s1 = bf2f(kr.y) * bf2f(qr.y) * inv * (D[4 * hd + 1] + bev.y);
                    const float s2 = bf2f(kr.z) * bf2f(qr.z) * inv * (D[4 * hd + 2] + bev.z);
                    const float s3 = bf2f(kr.w) * bf2f(qr.w) * inv * (D[4 * hd + 3] + bev.w);
                    const int c4 = (2 * hd + hi) ^ (lid & 7);       // XOR swizzle
                    buf[lid * 8 + c4] = make_float4(s0, s1, s2, s3);
                    float pp = (s0 + s1) + (s2 + s3);
                    const float full = pp + __shfl_xor(pp, 32);     // head = 4jh+hd
                    gate[jh * 4 + hd] = expf(fminf(fmaxf(full, -5.f), 5.f));
                }

                // readout: 4 x 64-lane dwordx4 stores of 128B half-rows
                const int r8 = lane >> 3, m = lane & 7;
#pragma unroll
                for (int it = 0; it < 4; ++it) {
                    const int row = it * 8 + r8;                    // edge row 0..31
                    const int edge2 = base + eh * 32 + row;
                    const float4 v = buf[row * 8 + (m ^ (row & 7))];
                    if (edge2 < E)
                        *((float4*)e_out + (size_t)edge2 * 16 + jh * 8 + m) = v;
                }
            }

            // coalesced bf16 gate write: 32 edges x 16B contiguous
            if (erow_i < E) {
                const ushort4 g = (hi == 0)
                    ? make_ushort4(f2bfu(gate[0]), f2bfu(gate[1]), f2bfu(gate[2]), f2bfu(gate[3]))
                    : make_ushort4(f2bfu(gate[4]), f2bfu(gate[5]), f2bfu(gate[6]), f2bfu(gate[7]));
                *(ushort4*)(sg + (size_t)erow_i * 8 + hi * 4) = g;
            }
        }
    }
}

// ---------------- reorder kernel: coalesced read -> sorted scatter (bf16) ----------------
__global__ __launch_bounds__(256)
void reorder_kernel(const unsigned short* __restrict__ sg, const int* __restrict__ src,
                    const int* __restrict__ dst, const int* __restrict__ rank,
                    const int* __restrict__ offs,
                    unsigned short* __restrict__ s_sorted, int* __restrict__ src_sorted,
                    int E)
{
    int i = blockIdx.x * 256 + threadIdx.x;
    const int stride = gridDim.x * 256;
    for (; i < E; i += stride) {
        const int rk = offs[dst[i]] + rank[i];
        const uint4 g = *(const uint4*)(sg + (size_t)i * 8);     // 16B = 8 bf16
        *(uint4*)(s_sorted + (size_t)rk * 8) = g;
        src_sorted[rk] = src[i];
    }
}

// ---------------- aggregation: one wave per node, bf16 V + bf16 gates ----------------
__global__ __launch_bounds__(64, 8)
void aggregate_kernel(const int* __restrict__ offsets,
                      const int* __restrict__ src_sorted,
                      const unsigned short* __restrict__ s_sorted,
                      const unsigned short* __restrict__ V,
                      float* __restrict__ hout, int n)
{
    const int w = blockIdx.x;           // one wave = one block = one node
    const int lane = threadIdx.x;
    if (w >= n) return;
    const int o0 = offsets[w], o1 = offsets[w + 1];
    const int head = lane >> 3;
    float acc = 0.f, zacc = 0.f;
    int j = o0;
    for (; j + 8 <= o1; j += 8) {
        int   sv[8];
        float ss[8];
#pragma unroll
        for (int q = 0; q < 8; ++q) {
            sv[q] = src_sorted[j + q];
            ss[q] = bf2f(s_sorted[(size_t)(j + q) * 8 + head]);
        }
        float vv[8];
#pragma unroll
        for (int q = 0; q < 8; ++q)
            vv[q] = bf2f(V[(size_t)sv[q] * 64 + lane]);
#pragma unroll
        for (int q = 0; q < 8; ++q) {
            acc = fmaf(vv[q], ss[q], acc);
            zacc += ss[q];
        }
    }
    for (; j < o1; ++j) {
        const int sv = src_sorted[j];
        const float s = bf2f(s_sorted[(size_t)j * 8 + head]);
        acc = fmaf(bf2f(V[(size_t)sv * 64 + lane]), s, acc);
        zacc += s;
    }
    hout[(size_t)w * 64 + lane] = acc / (zacc + 1e-6f);
}

extern "C" void kernel_launch(void* const* d_in, const int* in_sizes, int n_in,
                              void* d_out, int out_size, void* d_ws, size_t ws_size,
                              hipStream_t stream)
{
    const float* h  = (const float*)d_in[0];
    const float* e  = (const float*)d_in[1];
    const float* Wq = (const float*)d_in[2];
    const float* bq = (const float*)d_in[3];
    const float* Wk = (const float*)d_in[4];
    const float* bk = (const float*)d_in[5];
    const float* Wv = (const float*)d_in[6];
    const float* bv = (const float*)d_in[7];
    const float* We = (const float*)d_in[8];
    const float* be = (const float*)d_in[9];
    const int* src  = (const int*)d_in[10];
    const int* dst  = (const int*)d_in[11];

    const int N = in_sizes[0] / 64;
    const int E = in_sizes[1] / 64;

    float* hout  = (float*)d_out;                    // [N*64]
    float* e_out = (float*)d_out + (size_t)N * 64;   // [E*64]

    // workspace layout
    char* ws = (char*)d_ws;
    unsigned short* Q = (unsigned short*)ws; ws += (size_t)N * 64 * sizeof(unsigned short);
    unsigned short* K = (unsigned short*)ws; ws += (size_t)N * 64 * sizeof(unsigned short);
    unsigned short* V = (unsigned short*)ws; ws += (size_t)N * 64 * sizeof(unsigned short);
    unsigned short* sg = (unsigned short*)ws;       ws += (size_t)E * 8 * sizeof(unsigned short);
    unsigned short* s_sorted = (unsigned short*)ws; ws += (size_t)E * 8 * sizeof(unsigned short);
    int* src_sorted = (int*)ws;            ws += (size_t)E * sizeof(int);
    int* rank = (int*)ws;                  ws += (size_t)E * sizeof(int);
    int* counts  = (int*)ws;               ws += (size_t)N * sizeof(int);
    int* offsets = (int*)ws;               ws += (size_t)(N + 1) * sizeof(int);
    int* bsum    = (int*)ws;               ws += 64 * sizeof(int);

    hipMemsetAsync(counts, 0, (size_t)N * sizeof(int), stream);

    // 1) fused Q,K,V projections (bf16 out) + rank (independent, overlapped)
    proj_rank_kernel<<<dim3(512, 4), dim3(256), 0, stream>>>(
        h, Wq, bq, Wk, bk, Wv, bv, Q, K, V, dst, counts, rank, N, E);

    // 2) exclusive scan -> offsets (multi-block, 3 kernels)
    const int nb = (N + 1023) / 1024;
    scan1_kernel<<<dim3(nb), dim3(1024), 0, stream>>>(counts, offsets, bsum, N);
    scan2_kernel<<<dim3(1), dim3(64), 0, stream>>>(bsum, nb);
    scan3_kernel<<<dim3(nb), dim3(1024), 0, stream>>>(offsets, bsum, N, E);

    // 3) edge pass: MFMA, dbuf LDS, bf16 K/Q gathers, bf16 gate writes
    edge_kernel<<<dim3(1280), dim3(256), 0, stream>>>(
        e, We, be, src, dst, Q, K, e_out, sg, E);

    // 4) reorder: coalesced bf16 reads -> sorted scatter (TLP-rich)
    reorder_kernel<<<dim3(2048), dim3(256), 0, stream>>>(
        sg, src, dst, rank, offsets, s_sorted, src_sorted, E);

    // 5) aggregate: one 64-thread block per node, bf16 V + gates
    aggregate_kernel<<<dim3(N), dim3(64), 0, stream>>>(
        offsets, src_sorted, s_sorted, V, hout, N);
}